// Round 1
// baseline (99.632 us; speedup 1.0000x reference)
//
#include <hip/hip_runtime.h>
#include <math.h>

// Problem constants (match reference setup_inputs)
#define BS 32
#define NA 3
#define NC 80
#define HH 52
#define WW 52
#define TPER 50                 // targets per batch image
#define NTT (BS * TPER)         // 1600 total targets
#define HW (HH * WW)            // 2704
#define CPB (NA * HW)           // 8112 cells per batch image
#define CH (5 + NC)             // 85 channels per anchor

__device__ __forceinline__ float sigm(float v) { return 1.0f / (1.0f + expf(-v)); }

// Workspace float layout:
//   acc[0..15]  : 0:lx 1:ly 2:lw 3:lh 4:conf_obj 5:conf_noobj 6:lcls 7:aloss 8:n_valid
//   tf[9][NTT]  : 0:tx 1:ty 2:tw 3:th 4:x1 5:x2 6:y1 7:y2 8:area
//   ti[2][NTT]  : 0:cell (best_n*HW + gj*WW + gi, -1 if invalid) 1:cls

__global__ __launch_bounds__(256) void k_targets(const float* __restrict__ tgt,
                                                 float* __restrict__ acc,
                                                 float* __restrict__ tf,
                                                 int* __restrict__ ti)
{
    const int tid = threadIdx.x;
    if (tid < 16) acc[tid] = 0.0f;
    __syncthreads();
    const float aw[3] = {1.25f, 2.0f, 4.125f};
    const float ah[3] = {1.625f, 3.75f, 2.875f};
    int local = 0;
    for (int i = tid; i < NTT; i += 256) {
        const float* p = tgt + (size_t)i * 5;
        float c0 = p[0], c1 = p[1], c2 = p[2], c3 = p[3], c4 = p[4];
        bool valid = (c0 + c1 + c2 + c3 + c4) > 0.0f;
        float gx = c1 * WW, gy = c2 * HH, gw = c3 * WW, gh = c4 * HH;
        int gi = (int)gx; gi = gi < 0 ? 0 : (gi > WW - 1 ? WW - 1 : gi);
        int gj = (int)gy; gj = gj < 0 ? 0 : (gj > HH - 1 ? HH - 1 : gj);
        int bn = 0; float best = -1.0f;
        for (int a = 0; a < 3; ++a) {
            float inter = fminf(gw, aw[a]) * fminf(gh, ah[a]);
            float uni = gw * gh + aw[a] * ah[a] - inter;
            float iou = inter / (uni + 1e-16f);
            if (iou > best) { best = iou; bn = a; }   // strict > keeps first (argmax tie rule)
        }
        tf[0 * NTT + i] = gx - (float)gi;
        tf[1 * NTT + i] = gy - (float)gj;
        tf[2 * NTT + i] = logf(gw / aw[bn] + 1e-16f);
        tf[3 * NTT + i] = logf(gh / ah[bn] + 1e-16f);
        tf[4 * NTT + i] = gx - 0.5f * gw;
        tf[5 * NTT + i] = gx + 0.5f * gw;
        tf[6 * NTT + i] = gy - 0.5f * gh;
        tf[7 * NTT + i] = gy + 0.5f * gh;
        tf[8 * NTT + i] = gw * gh;
        int cls = (int)c0; cls = cls < 0 ? 0 : (cls > NC - 1 ? NC - 1 : cls);
        ti[0 * NTT + i] = valid ? (bn * HW + gj * WW + gi) : -1;
        ti[1 * NTT + i] = cls;
        if (valid) ++local;
    }
    atomicAdd(&acc[8], (float)local);
}

// Dense per-cell kernel: noobj conf BCE + anchor-prior (a_loss) terms.
__global__ __launch_bounds__(256) void k_cells(const float* __restrict__ in,
                                               const float* __restrict__ tf,
                                               const int* __restrict__ ti,
                                               float* __restrict__ acc)
{
    __shared__ float sx1[TPER], sx2[TPER], sy1[TPER], sy2[TPER], sar[TPER];
    __shared__ int scell[TPER];
    const int b = blockIdx.x;
    const int tid = threadIdx.x;
    if (tid < TPER) {
        int i = b * TPER + tid;
        sx1[tid] = tf[4 * NTT + i];
        sx2[tid] = tf[5 * NTT + i];
        sy1[tid] = tf[6 * NTT + i];
        sy2[tid] = tf[7 * NTT + i];
        sar[tid] = tf[8 * NTT + i];
        scell[tid] = ti[i];
    }
    __syncthreads();
    const float aw[3] = {1.25f, 2.0f, 4.125f};
    const float ah[3] = {1.625f, 3.75f, 2.875f};
    const int idx = blockIdx.y * 256 + tid;
    float noobj_term = 0.0f, aterm = 0.0f;
    if (idx < CPB) {
        int a = idx / HW;
        int r = idx - a * HW;
        int yy = r / WW;
        int xx = r - yy * WW;
        const float* base = in + ((size_t)b * (NA * CH) + a * CH) * HW + r;
        float xr = base[0], yr = base[HW], wr = base[2 * HW], hr = base[3 * HW], cr = base[4 * HW];
        float sx = sigm(xr), sy = sigm(yr), conf = sigm(cr);
        float px = sx + (float)xx, py = sy + (float)yy;
        float pw = expf(wr) * aw[a], ph = expf(hr) * ah[a];
        float p1 = px - 0.5f * pw, p2 = px + 0.5f * pw;
        float q1 = py - 0.5f * ph, q2 = py + 0.5f * ph;
        float area2 = pw * ph;
        bool ignore = false, istgt = false;
        #pragma unroll 5
        for (int t = 0; t < TPER; ++t) {
            int c = scell[t];
            if (c < 0) continue;                    // invalid target
            float iw = fminf(sx2[t], p2) - fmaxf(sx1[t], p1); iw = fmaxf(iw, 0.0f);
            float ih = fminf(sy2[t], q2) - fmaxf(sy1[t], q1); ih = fmaxf(ih, 0.0f);
            float inter = iw * ih;
            float iou = inter / (sar[t] + area2 - inter + 1e-16f);
            ignore = ignore || (iou >= 0.5f);
            istgt = istgt || (c == idx);
        }
        if (!ignore && !istgt) noobj_term = -logf(fmaxf(1.0f - conf, 1e-12f));
        aterm = (sx - 0.5f) * (sx - 0.5f) + (sy - 0.5f) * (sy - 0.5f) + wr * wr + hr * hr;
    }
    __shared__ float red[256];
    red[tid] = noobj_term; __syncthreads();
    for (int s = 128; s > 0; s >>= 1) { if (tid < s) red[tid] += red[tid + s]; __syncthreads(); }
    if (tid == 0) atomicAdd(&acc[5], red[0]);
    __syncthreads();
    red[tid] = aterm; __syncthreads();
    for (int s = 128; s > 0; s >>= 1) { if (tid < s) red[tid] += red[tid + s]; __syncthreads(); }
    if (tid == 0) atomicAdd(&acc[7], red[0]);
}

// Per-target kernel: xywh MSE + conf-obj + multi-hot class BCE, with
// last-valid-writer-wins ownership per cell (matches in-order scatter .set).
__global__ __launch_bounds__(256) void k_obj(const float* __restrict__ in,
                                             const float* __restrict__ tf,
                                             const int* __restrict__ ti,
                                             float* __restrict__ acc)
{
    const int i = blockIdx.x * 256 + threadIdx.x;
    if (i >= NTT) return;
    const int cell = ti[i];
    if (cell < 0) return;
    const int b = i / TPER;
    const int t = i - b * TPER;
    for (int t2 = t + 1; t2 < TPER; ++t2)       // a later valid target owns this cell
        if (ti[b * TPER + t2] == cell) return;
    int a = cell / HW;
    int r = cell - a * HW;
    const float* base = in + ((size_t)b * (NA * CH) + a * CH) * HW + r;
    float xr = base[0], yr = base[HW], wr = base[2 * HW], hr = base[3 * HW], cr = base[4 * HW];
    float sx = sigm(xr), sy = sigm(yr), conf = sigm(cr);
    float dx = sx - tf[0 * NTT + i];
    float dy = sy - tf[1 * NTT + i];
    float dw = wr - tf[2 * NTT + i];
    float dh = hr - tf[3 * NTT + i];
    atomicAdd(&acc[0], dx * dx);
    atomicAdd(&acc[1], dy * dy);
    atomicAdd(&acc[2], dw * dw);
    atomicAdd(&acc[3], dh * dh);
    atomicAdd(&acc[4], -logf(fmaxf(conf, 1e-12f)));
    // union of classes of all valid targets mapping to this cell (tcls is multi-hot on collision)
    unsigned cm0 = 0, cm1 = 0, cm2 = 0;
    for (int t2 = 0; t2 < TPER; ++t2) {
        int j = b * TPER + t2;
        if (ti[j] == cell) {
            int c = ti[NTT + j];
            if (c < 32) cm0 |= 1u << c;
            else if (c < 64) cm1 |= 1u << (c - 32);
            else cm2 |= 1u << (c - 64);
        }
    }
    float lc = 0.0f;
    for (int c = 0; c < NC; ++c) {
        float p = sigm(base[(size_t)(5 + c) * HW]);
        unsigned bit = (c < 32) ? ((cm0 >> c) & 1u)
                     : (c < 64) ? ((cm1 >> (c - 32)) & 1u)
                                : ((cm2 >> (c - 64)) & 1u);
        lc += bit ? -logf(fmaxf(p, 1e-12f)) : -logf(fmaxf(1.0f - p, 1e-12f));
    }
    atomicAdd(&acc[6], lc);
}

__global__ void k_final(const float* __restrict__ acc, float* __restrict__ out)
{
    float n = fmaxf(acc[8], 1.0f);
    float loss = (acc[0] + acc[1] + acc[2] + acc[3]) / (2.0f * n)   // xy (L=1) + wh (L=1)
               + 5.0f * (acc[4] + 0.2f * acc[5]) / n                // conf, LAMBDA_CONF=5
               + acc[6] / n                                         // cls, LAMBDA_CLS=1
               + 0.1f * (acc[7] / (2.0f * n));                      // anchor-prior a_loss
    out[0] = loss;
}

extern "C" void kernel_launch(void* const* d_in, const int* in_sizes, int n_in,
                              void* d_out, int out_size, void* d_ws, size_t ws_size,
                              hipStream_t stream)
{
    const float* in = (const float*)d_in[0];
    const float* tgt = (const float*)d_in[1];
    float* acc = (float*)d_ws;
    float* tf = acc + 16;
    int* ti = (int*)(tf + 9 * NTT);

    k_targets<<<1, 256, 0, stream>>>(tgt, acc, tf, ti);
    dim3 g2(BS, (CPB + 255) / 256);
    k_cells<<<g2, 256, 0, stream>>>(in, tf, ti, acc);
    k_obj<<<(NTT + 255) / 256, 256, 0, stream>>>(in, tf, ti, acc);
    k_final<<<1, 1, 0, stream>>>(acc, (float*)d_out);
}

// Round 2
// 94.915 us; speedup vs baseline: 1.0497x; 1.0497x over previous
//
#include <hip/hip_runtime.h>
#include <math.h>

// Problem constants (match reference setup_inputs)
#define BS 32
#define NA 3
#define NC 80
#define HH 52
#define WW 52
#define TPER 50                 // targets per batch image
#define NTT (BS * TPER)         // 1600 total targets
#define HW (HH * WW)            // 2704
#define CPB (NA * HW)           // 8112 cells per batch image
#define CH (5 + NC)             // 85 channels per anchor

__device__ __forceinline__ float sigm(float v) { return 1.0f / (1.0f + expf(-v)); }

// Workspace float layout:
//   acc[0..15]  : 0:lx 1:ly 2:lw 3:lh 4:conf_obj 5:conf_noobj 6:lcls 7:aloss 8:n_valid
//   tf[9][NTT]  : 0:tx 1:ty 2:tw 3:th 4:x1 5:x2 6:y1 7:y2 8:area
//   ti[2][NTT]  : 0:cell (best_n*HW + gj*WW + gi, -1 if invalid) 1:cls

__global__ __launch_bounds__(256) void k_targets(const float* __restrict__ tgt,
                                                 float* __restrict__ acc,
                                                 float* __restrict__ tf,
                                                 int* __restrict__ ti)
{
    const int tid = threadIdx.x;
    if (tid < 16) acc[tid] = 0.0f;
    __syncthreads();
    const float aw[3] = {1.25f, 2.0f, 4.125f};
    const float ah[3] = {1.625f, 3.75f, 2.875f};
    int local = 0;
    for (int i = tid; i < NTT; i += 256) {
        const float* p = tgt + (size_t)i * 5;
        float c0 = p[0], c1 = p[1], c2 = p[2], c3 = p[3], c4 = p[4];
        bool valid = (c0 + c1 + c2 + c3 + c4) > 0.0f;
        float gx = c1 * WW, gy = c2 * HH, gw = c3 * WW, gh = c4 * HH;
        int gi = (int)gx; gi = gi < 0 ? 0 : (gi > WW - 1 ? WW - 1 : gi);
        int gj = (int)gy; gj = gj < 0 ? 0 : (gj > HH - 1 ? HH - 1 : gj);
        int bn = 0; float best = -1.0f;
        for (int a = 0; a < 3; ++a) {
            float inter = fminf(gw, aw[a]) * fminf(gh, ah[a]);
            float uni = gw * gh + aw[a] * ah[a] - inter;
            float iou = inter / (uni + 1e-16f);
            if (iou > best) { best = iou; bn = a; }   // strict > keeps first (argmax tie rule)
        }
        tf[0 * NTT + i] = gx - (float)gi;
        tf[1 * NTT + i] = gy - (float)gj;
        tf[2 * NTT + i] = logf(gw / aw[bn] + 1e-16f);
        tf[3 * NTT + i] = logf(gh / ah[bn] + 1e-16f);
        tf[4 * NTT + i] = gx - 0.5f * gw;
        tf[5 * NTT + i] = gx + 0.5f * gw;
        tf[6 * NTT + i] = gy - 0.5f * gh;
        tf[7 * NTT + i] = gy + 0.5f * gh;
        tf[8 * NTT + i] = gw * gh;
        int cls = (int)c0; cls = cls < 0 ? 0 : (cls > NC - 1 ? NC - 1 : cls);
        ti[0 * NTT + i] = valid ? (bn * HW + gj * WW + gi) : -1;
        ti[1 * NTT + i] = cls;
        if (valid) ++local;
    }
    atomicAdd(&acc[8], (float)local);
}

// Dense per-cell kernel: noobj conf BCE + anchor-prior (a_loss) terms.
__global__ __launch_bounds__(256) void k_cells(const float* __restrict__ in,
                                               const float* __restrict__ tf,
                                               const int* __restrict__ ti,
                                               float* __restrict__ acc)
{
    __shared__ float sx1[TPER], sx2[TPER], sy1[TPER], sy2[TPER], sar[TPER];
    __shared__ int scell[TPER];
    const int b = blockIdx.x;
    const int tid = threadIdx.x;
    if (tid < TPER) {
        int i = b * TPER + tid;
        sx1[tid] = tf[4 * NTT + i];
        sx2[tid] = tf[5 * NTT + i];
        sy1[tid] = tf[6 * NTT + i];
        sy2[tid] = tf[7 * NTT + i];
        sar[tid] = tf[8 * NTT + i];
        scell[tid] = ti[i];
    }
    __syncthreads();
    const float aw[3] = {1.25f, 2.0f, 4.125f};
    const float ah[3] = {1.625f, 3.75f, 2.875f};
    const int idx = blockIdx.y * 256 + tid;
    float noobj_term = 0.0f, aterm = 0.0f;
    if (idx < CPB) {
        int a = idx / HW;
        int r = idx - a * HW;
        int yy = r / WW;
        int xx = r - yy * WW;
        const float* base = in + ((size_t)b * (NA * CH) + a * CH) * HW + r;
        float xr = base[0], yr = base[HW], wr = base[2 * HW], hr = base[3 * HW], cr = base[4 * HW];
        float sx = sigm(xr), sy = sigm(yr), conf = sigm(cr);
        float px = sx + (float)xx, py = sy + (float)yy;
        float pw = expf(wr) * aw[a], ph = expf(hr) * ah[a];
        float p1 = px - 0.5f * pw, p2 = px + 0.5f * pw;
        float q1 = py - 0.5f * ph, q2 = py + 0.5f * ph;
        float area2 = pw * ph;
        bool ignore = false, istgt = false;
        #pragma unroll 5
        for (int t = 0; t < TPER; ++t) {
            int c = scell[t];
            if (c < 0) continue;                    // invalid target
            float iw = fminf(sx2[t], p2) - fmaxf(sx1[t], p1); iw = fmaxf(iw, 0.0f);
            float ih = fminf(sy2[t], q2) - fmaxf(sy1[t], q1); ih = fmaxf(ih, 0.0f);
            float inter = iw * ih;
            float iou = inter / (sar[t] + area2 - inter + 1e-16f);
            ignore = ignore || (iou >= 0.5f);
            istgt = istgt || (c == idx);
        }
        if (!ignore && !istgt) noobj_term = -logf(fmaxf(1.0f - conf, 1e-12f));
        aterm = (sx - 0.5f) * (sx - 0.5f) + (sy - 0.5f) * (sy - 0.5f) + wr * wr + hr * hr;
    }
    __shared__ float red[256];
    red[tid] = noobj_term; __syncthreads();
    for (int s = 128; s > 0; s >>= 1) { if (tid < s) red[tid] += red[tid + s]; __syncthreads(); }
    if (tid == 0) atomicAdd(&acc[5], red[0]);
    __syncthreads();
    red[tid] = aterm; __syncthreads();
    for (int s = 128; s > 0; s >>= 1) { if (tid < s) red[tid] += red[tid + s]; __syncthreads(); }
    if (tid == 0) atomicAdd(&acc[7], red[0]);
}

// Per-target kernel: ONE BLOCK PER TARGET (1600 blocks x 128 threads).
// Lanes 0..79: class-BCE term for class==lane. Lanes 80..84: x/y/w/h/conf.
// Ownership: last valid target writing the cell owns it (in-order scatter).
// tcls on collision is multi-hot (union of classes of all targets in cell).
__global__ __launch_bounds__(128) void k_obj(const float* __restrict__ in,
                                             const float* __restrict__ tf,
                                             const int* __restrict__ ti,
                                             float* __restrict__ acc)
{
    __shared__ int scell[TPER], scls[TPER];
    __shared__ float red[128];
    const int i = blockIdx.x;              // target index
    const int b = i / TPER;
    const int t = i - b * TPER;
    const int tid = threadIdx.x;
    if (tid < TPER) {
        scell[tid] = ti[b * TPER + tid];
        scls[tid]  = ti[NTT + b * TPER + tid];
    }
    __syncthreads();
    const int cell = scell[t];
    bool owner = (cell >= 0);
    if (owner) {
        for (int t2 = t + 1; t2 < TPER; ++t2)
            if (scell[t2] == cell) { owner = false; break; }
    }
    if (!owner) return;                    // uniform across block — safe
    const int a = cell / HW;
    const int r = cell - a * HW;
    const float* base = in + ((size_t)b * (NA * CH) + a * CH) * HW + r;

    float cterm = 0.0f;
    if (tid < NC) {
        bool pos = false;
        for (int t2 = 0; t2 < TPER; ++t2)
            if (scell[t2] == cell && scls[t2] == tid) { pos = true; break; }
        float p = sigm(base[(size_t)(5 + tid) * HW]);
        cterm = pos ? -logf(fmaxf(p, 1e-12f)) : -logf(fmaxf(1.0f - p, 1e-12f));
    } else if (tid < 85) {
        // overlap the 5 box/conf loads with the class loads
        int k = tid - NC;                  // 0..4 -> x,y,w,h,conf channel
        float v = base[(size_t)k * HW];
        float term;
        if (k == 0)      { float d = sigm(v) - tf[0 * NTT + i]; term = d * d; }
        else if (k == 1) { float d = sigm(v) - tf[1 * NTT + i]; term = d * d; }
        else if (k == 2) { float d = v - tf[2 * NTT + i];       term = d * d; }
        else if (k == 3) { float d = v - tf[3 * NTT + i];       term = d * d; }
        else             { term = -logf(fmaxf(sigm(v), 1e-12f)); }
        atomicAdd(&acc[k], term);
    }
    red[tid] = cterm; __syncthreads();
    for (int s = 64; s > 0; s >>= 1) { if (tid < s) red[tid] += red[tid + s]; __syncthreads(); }
    if (tid == 0) atomicAdd(&acc[6], red[0]);
}

__global__ void k_final(const float* __restrict__ acc, float* __restrict__ out)
{
    float n = fmaxf(acc[8], 1.0f);
    float loss = (acc[0] + acc[1] + acc[2] + acc[3]) / (2.0f * n)   // xy (L=1) + wh (L=1)
               + 5.0f * (acc[4] + 0.2f * acc[5]) / n                // conf, LAMBDA_CONF=5
               + acc[6] / n                                         // cls, LAMBDA_CLS=1
               + 0.1f * (acc[7] / (2.0f * n));                      // anchor-prior a_loss
    out[0] = loss;
}

extern "C" void kernel_launch(void* const* d_in, const int* in_sizes, int n_in,
                              void* d_out, int out_size, void* d_ws, size_t ws_size,
                              hipStream_t stream)
{
    const float* in = (const float*)d_in[0];
    const float* tgt = (const float*)d_in[1];
    float* acc = (float*)d_ws;
    float* tf = acc + 16;
    int* ti = (int*)(tf + 9 * NTT);

    k_targets<<<1, 256, 0, stream>>>(tgt, acc, tf, ti);
    dim3 g2(BS, (CPB + 255) / 256);
    k_cells<<<g2, 256, 0, stream>>>(in, tf, ti, acc);
    k_obj<<<NTT, 128, 0, stream>>>(in, tf, ti, acc);
    k_final<<<1, 1, 0, stream>>>(acc, (float*)d_out);
}

// Round 3
// 40.023 us; speedup vs baseline: 2.4894x; 2.3715x over previous
//
#include <hip/hip_runtime.h>
#include <math.h>

// Problem constants (match reference setup_inputs)
#define BS 32
#define NA 3
#define NC 80
#define HH 52
#define WW 52
#define TPER 50                 // targets per batch image
#define NTT (BS * TPER)         // 1600 total targets
#define HW (HH * WW)            // 2704
#define CPB (NA * HW)           // 8112 cells per batch image
#define CH (5 + NC)             // 85 channels per anchor
#define NCB 32                  // y-blocks per batch: 32*256 = 8192 >= 8112
#define NCELLBLK (BS * NCB)     // 1024 k_cells blocks

__device__ __forceinline__ float sigm(float v) { return 1.0f / (1.0f + expf(-v)); }

// Workspace float layout (all written every call, no atomics anywhere):
//   pc[NCELLBLK][2] : per-cells-block partials {noobj_bce, aloss}
//   po[NTT][6]      : per-target partials {dx2, dy2, dw2, dh2, conf_obj, cls_bce}

// Dense per-cell kernel: noobj conf BCE + anchor-prior (a_loss).
// Per-batch target table recomputed in LDS by tid<50 (no separate prep kernel).
__global__ __launch_bounds__(256) void k_cells(const float* __restrict__ in,
                                               const float* __restrict__ tgt,
                                               float* __restrict__ pc)
{
    __shared__ float sx1[TPER], sx2[TPER], sy1[TPER], sy2[TPER], sar[TPER];
    __shared__ int scell[TPER];
    const int b = blockIdx.x;
    const int tid = threadIdx.x;
    if (tid < TPER) {
        const float* p = tgt + (size_t)(b * TPER + tid) * 5;
        float c0 = p[0], c1 = p[1], c2 = p[2], c3 = p[3], c4 = p[4];
        bool valid = (c0 + c1 + c2 + c3 + c4) > 0.0f;
        float gx = c1 * WW, gy = c2 * HH, gw = c3 * WW, gh = c4 * HH;
        int gi = (int)gx; gi = gi < 0 ? 0 : (gi > WW - 1 ? WW - 1 : gi);
        int gj = (int)gy; gj = gj < 0 ? 0 : (gj > HH - 1 ? HH - 1 : gj);
        const float aw[3] = {1.25f, 2.0f, 4.125f};
        const float ah[3] = {1.625f, 3.75f, 2.875f};
        int bn = 0; float best = -1.0f;
        for (int a = 0; a < 3; ++a) {
            float inter = fminf(gw, aw[a]) * fminf(gh, ah[a]);
            float uni = gw * gh + aw[a] * ah[a] - inter;
            float iou = inter / (uni + 1e-16f);
            if (iou > best) { best = iou; bn = a; }     // strict >: argmax keeps first on tie
        }
        sx1[tid] = gx - 0.5f * gw;
        sx2[tid] = gx + 0.5f * gw;
        sy1[tid] = gy - 0.5f * gh;
        sy2[tid] = gy + 0.5f * gh;
        sar[tid] = gw * gh;
        scell[tid] = valid ? (bn * HW + gj * WW + gi) : -1;
    }
    __syncthreads();
    const float aw[3] = {1.25f, 2.0f, 4.125f};
    const float ah[3] = {1.625f, 3.75f, 2.875f};
    const int idx = blockIdx.y * 256 + tid;
    float noobj_term = 0.0f, aterm = 0.0f;
    if (idx < CPB) {
        int a = idx / HW;
        int r = idx - a * HW;
        int yy = r / WW;
        int xx = r - yy * WW;
        const float* base = in + ((size_t)b * (NA * CH) + a * CH) * HW + r;
        float xr = base[0], yr = base[HW], wr = base[2 * HW], hr = base[3 * HW], cr = base[4 * HW];
        float sx = sigm(xr), sy = sigm(yr), conf = sigm(cr);
        float px = sx + (float)xx, py = sy + (float)yy;
        float pw = expf(wr) * aw[a], ph = expf(hr) * ah[a];
        float p1 = px - 0.5f * pw, p2 = px + 0.5f * pw;
        float q1 = py - 0.5f * ph, q2 = py + 0.5f * ph;
        float area2 = pw * ph;
        bool ignore = false, istgt = false;
        #pragma unroll 5
        for (int t = 0; t < TPER; ++t) {
            int c = scell[t];
            if (c < 0) continue;                        // invalid target
            float iw = fminf(sx2[t], p2) - fmaxf(sx1[t], p1); iw = fmaxf(iw, 0.0f);
            float ih = fminf(sy2[t], q2) - fmaxf(sy1[t], q1); ih = fmaxf(ih, 0.0f);
            float inter = iw * ih;
            float iou = inter / (sar[t] + area2 - inter + 1e-16f);
            ignore = ignore || (iou >= 0.5f);
            istgt = istgt || (c == idx);
        }
        if (!ignore && !istgt) noobj_term = -logf(fmaxf(1.0f - conf, 1e-12f));
        aterm = (sx - 0.5f) * (sx - 0.5f) + (sy - 0.5f) * (sy - 0.5f) + wr * wr + hr * hr;
    }
    __shared__ float red[256];
    red[tid] = noobj_term; __syncthreads();
    for (int s = 128; s > 0; s >>= 1) { if (tid < s) red[tid] += red[tid + s]; __syncthreads(); }
    float* my = pc + (size_t)(b * NCB + blockIdx.y) * 2;
    if (tid == 0) my[0] = red[0];
    __syncthreads();
    red[tid] = aterm; __syncthreads();
    for (int s = 128; s > 0; s >>= 1) { if (tid < s) red[tid] += red[tid + s]; __syncthreads(); }
    if (tid == 0) my[1] = red[0];
}

// Per-target kernel: ONE BLOCK PER TARGET (1600 x 128). Atomic-free:
// writes 6 partials to po[i][0..5]. Lanes 0..79: class BCE. Lanes 80..84:
// x/y/w/h/conf. Ownership: last valid target writing a cell owns it
// (in-order scatter); tcls is multi-hot union on collision.
__global__ __launch_bounds__(128) void k_obj(const float* __restrict__ in,
                                             const float* __restrict__ tgt,
                                             float* __restrict__ po)
{
    __shared__ int scell[TPER], scls[TPER];
    __shared__ float red[128];
    __shared__ float sterm[5];
    const int i = blockIdx.x;              // target index
    const int b = i / TPER;
    const int t = i - b * TPER;
    const int tid = threadIdx.x;
    if (tid < TPER) {
        const float* p = tgt + (size_t)(b * TPER + tid) * 5;
        float c0 = p[0], c1 = p[1], c2 = p[2], c3 = p[3], c4 = p[4];
        bool valid = (c0 + c1 + c2 + c3 + c4) > 0.0f;
        float gx = c1 * WW, gy = c2 * HH, gw = c3 * WW, gh = c4 * HH;
        int gi = (int)gx; gi = gi < 0 ? 0 : (gi > WW - 1 ? WW - 1 : gi);
        int gj = (int)gy; gj = gj < 0 ? 0 : (gj > HH - 1 ? HH - 1 : gj);
        const float aw[3] = {1.25f, 2.0f, 4.125f};
        const float ah[3] = {1.625f, 3.75f, 2.875f};
        int bn = 0; float best = -1.0f;
        for (int a = 0; a < 3; ++a) {
            float inter = fminf(gw, aw[a]) * fminf(gh, ah[a]);
            float uni = gw * gh + aw[a] * ah[a] - inter;
            float iou = inter / (uni + 1e-16f);
            if (iou > best) { best = iou; bn = a; }
        }
        scell[tid] = valid ? (bn * HW + gj * WW + gi) : -1;
        int cls = (int)c0; cls = cls < 0 ? 0 : (cls > NC - 1 ? NC - 1 : cls);
        scls[tid] = cls;
    }
    __syncthreads();
    const int cell = scell[t];
    bool owner = (cell >= 0);
    if (owner) {
        for (int t2 = t + 1; t2 < TPER; ++t2)
            if (scell[t2] == cell) { owner = false; break; }
    }
    float* my = po + (size_t)i * 6;
    if (!owner) {                           // uniform across block — safe
        if (tid < 6) my[tid] = 0.0f;
        return;
    }
    const int a = cell / HW;
    const int r = cell - a * HW;
    const float* base = in + ((size_t)b * (NA * CH) + a * CH) * HW + r;

    float cterm = 0.0f;
    if (tid < NC) {
        bool pos = false;
        for (int t2 = 0; t2 < TPER; ++t2)
            if (scell[t2] == cell && scls[t2] == tid) { pos = true; break; }
        float p = sigm(base[(size_t)(5 + tid) * HW]);
        cterm = pos ? -logf(fmaxf(p, 1e-12f)) : -logf(fmaxf(1.0f - p, 1e-12f));
    } else if (tid < 85) {
        int k = tid - NC;                   // 0..4 -> x,y,w,h,conf channel
        float v = base[(size_t)k * HW];
        const float* p = tgt + (size_t)i * 5;
        float term;
        if (k == 0) {
            float gx = p[1] * WW; int gi = (int)gx; gi = gi < 0 ? 0 : (gi > WW - 1 ? WW - 1 : gi);
            float d = sigm(v) - (gx - (float)gi); term = d * d;
        } else if (k == 1) {
            float gy = p[2] * HH; int gj = (int)gy; gj = gj < 0 ? 0 : (gj > HH - 1 ? HH - 1 : gj);
            float d = sigm(v) - (gy - (float)gj); term = d * d;
        } else if (k == 2) {
            const float aw_[3] = {1.25f, 2.0f, 4.125f};
            float d = v - logf(p[3] * WW / aw_[a] + 1e-16f); term = d * d;
        } else if (k == 3) {
            const float ah_[3] = {1.625f, 3.75f, 2.875f};
            float d = v - logf(p[4] * HH / ah_[a] + 1e-16f); term = d * d;
        } else {
            term = -logf(fmaxf(sigm(v), 1e-12f));
        }
        sterm[k] = term;
    }
    red[tid] = cterm; __syncthreads();
    for (int s = 64; s > 0; s >>= 1) { if (tid < s) red[tid] += red[tid + s]; __syncthreads(); }
    if (tid == 0) {
        my[0] = sterm[0]; my[1] = sterm[1]; my[2] = sterm[2];
        my[3] = sterm[3]; my[4] = sterm[4]; my[5] = red[0];
    }
}

// Single-block final reduce: sums all partials + counts valid targets.
__global__ __launch_bounds__(256) void k_final(const float* __restrict__ tgt,
                                               const float* __restrict__ pc,
                                               const float* __restrict__ po,
                                               float* __restrict__ out)
{
    const int tid = threadIdx.x;
    float s0 = 0, s1 = 0, s2 = 0, s3 = 0, s4 = 0, s5 = 0, noobj = 0, aterm = 0, nv = 0;
    for (int i = tid; i < NTT; i += 256) {
        const float* p = tgt + (size_t)i * 5;
        if (p[0] + p[1] + p[2] + p[3] + p[4] > 0.0f) nv += 1.0f;
        const float* q = po + (size_t)i * 6;
        s0 += q[0]; s1 += q[1]; s2 += q[2]; s3 += q[3]; s4 += q[4]; s5 += q[5];
    }
    for (int i = tid; i < NCELLBLK; i += 256) { noobj += pc[i * 2]; aterm += pc[i * 2 + 1]; }
    __shared__ float red[256];
    __shared__ float tot[9];
    float vals[9] = {s0, s1, s2, s3, s4, s5, noobj, aterm, nv};
    for (int k = 0; k < 9; ++k) {
        red[tid] = vals[k]; __syncthreads();
        for (int st = 128; st > 0; st >>= 1) { if (tid < st) red[tid] += red[tid + st]; __syncthreads(); }
        if (tid == 0) tot[k] = red[0];
        __syncthreads();
    }
    if (tid == 0) {
        float n = fmaxf(tot[8], 1.0f);
        float loss = (tot[0] + tot[1] + tot[2] + tot[3]) / (2.0f * n)  // xy + wh (lambda 1)
                   + 5.0f * (tot[4] + 0.2f * tot[6]) / n               // conf, LAMBDA_CONF=5
                   + tot[5] / n                                        // cls, LAMBDA_CLS=1
                   + 0.1f * (tot[7] / (2.0f * n));                     // anchor-prior a_loss
        out[0] = loss;
    }
}

extern "C" void kernel_launch(void* const* d_in, const int* in_sizes, int n_in,
                              void* d_out, int out_size, void* d_ws, size_t ws_size,
                              hipStream_t stream)
{
    const float* in = (const float*)d_in[0];
    const float* tgt = (const float*)d_in[1];
    float* pc = (float*)d_ws;              // [NCELLBLK][2]
    float* po = pc + NCELLBLK * 2;         // [NTT][6]

    dim3 gc(BS, NCB);
    k_cells<<<gc, 256, 0, stream>>>(in, tgt, pc);
    k_obj<<<NTT, 128, 0, stream>>>(in, tgt, po);
    k_final<<<1, 256, 0, stream>>>(tgt, pc, po, (float*)d_out);
}

// Round 4
// 31.303 us; speedup vs baseline: 3.1828x; 1.2786x over previous
//
#include <hip/hip_runtime.h>
#include <math.h>

// Problem constants (match reference setup_inputs)
#define BS 32
#define NA 3
#define NC 80
#define HH 52
#define WW 52
#define TPER 50                 // targets per batch image
#define NTT (BS * TPER)         // 1600 total targets
#define HW (HH * WW)            // 2704
#define CPB (NA * HW)           // 8112 cells per batch image
#define CH (5 + NC)             // 85 channels per anchor
#define NCB 32                  // y-blocks per batch: 32*256 = 8192 >= 8112
#define NCELLBLK (BS * NCB)     // 1024 cells-role blocks
#define NBLK (NCELLBLK + NTT)   // 2624 total blocks in k_main

__device__ __forceinline__ float sigm(float v) { return 1.0f / (1.0f + expf(-v)); }

// Workspace float layout (every slot written every call, no atomics):
//   ws[0..NBLK)        : per-block pre-weighted loss partial
//   ws[NBLK..NBLK+NTT) : per-target valid flag (0/1)

// Fused kernel. Blocks [0,NCELLBLK): dense cells role (noobj BCE + a_loss).
// Blocks [NCELLBLK,NBLK): per-target role (xywh MSE + conf-obj + class BCE).
// Each block emits ONE scalar: its pre-weighted contribution to n*loss.
__global__ __launch_bounds__(256) void k_main(const float* __restrict__ in,
                                              const float* __restrict__ tgt,
                                              float* __restrict__ ws)
{
    __shared__ float sx1[TPER], sx2[TPER], sy1[TPER], sy2[TPER], sar[TPER];
    __shared__ int scell[TPER], scls[TPER];
    __shared__ float red[256];
    __shared__ float sterm[5];
    const int tid = threadIdx.x;
    const float aw[3] = {1.25f, 2.0f, 4.125f};
    const float ah[3] = {1.625f, 3.75f, 2.875f};

    if (blockIdx.x < NCELLBLK) {
        // ---------------- cells role ----------------
        const int b  = blockIdx.x >> 5;            // / NCB
        const int yb = blockIdx.x & (NCB - 1);
        if (tid < TPER) {
            const float* p = tgt + (size_t)(b * TPER + tid) * 5;
            float c0 = p[0], c1 = p[1], c2 = p[2], c3 = p[3], c4 = p[4];
            bool valid = (c0 + c1 + c2 + c3 + c4) > 0.0f;
            float gx = c1 * WW, gy = c2 * HH, gw = c3 * WW, gh = c4 * HH;
            int gi = (int)gx; gi = gi < 0 ? 0 : (gi > WW - 1 ? WW - 1 : gi);
            int gj = (int)gy; gj = gj < 0 ? 0 : (gj > HH - 1 ? HH - 1 : gj);
            int bn = 0; float best = -1.0f;
            for (int a = 0; a < 3; ++a) {
                float inter = fminf(gw, aw[a]) * fminf(gh, ah[a]);
                float uni = gw * gh + aw[a] * ah[a] - inter;
                float iou = inter / (uni + 1e-16f);
                if (iou > best) { best = iou; bn = a; }   // strict >: argmax keeps first
            }
            if (valid) {
                sx1[tid] = gx - 0.5f * gw;
                sx2[tid] = gx + 0.5f * gw;
                sy1[tid] = gy - 0.5f * gh;
                sy2[tid] = gy + 0.5f * gh;
                sar[tid] = gw * gh;
                scell[tid] = bn * HW + gj * WW + gi;
            } else {                                   // branchless-neutral sentinels
                sx1[tid] = 1e30f; sx2[tid] = 1e30f;
                sy1[tid] = 1e30f; sy2[tid] = 1e30f;
                sar[tid] = 1e30f;
                scell[tid] = -1;
            }
        }
        __syncthreads();
        const int idx = yb * 256 + tid;
        float term = 0.0f;
        if (idx < CPB) {
            int a = idx / HW;
            int r = idx - a * HW;
            int yy = r / WW;
            int xx = r - yy * WW;
            const float* base = in + ((size_t)b * (NA * CH) + a * CH) * HW + r;
            float xr = base[0], yr = base[HW], wr = base[2 * HW], hr = base[3 * HW], cr = base[4 * HW];
            float sx = sigm(xr), sy = sigm(yr), conf = sigm(cr);
            float px = sx + (float)xx, py = sy + (float)yy;
            float pw = expf(wr) * aw[a], ph = expf(hr) * ah[a];
            float p1 = px - 0.5f * pw, p2 = px + 0.5f * pw;
            float q1 = py - 0.5f * ph, q2 = py + 0.5f * ph;
            float area2c = pw * ph + 1e-16f;
            bool ignore = false, istgt = false;
            #pragma unroll 10
            for (int t = 0; t < TPER; ++t) {
                float iw = fminf(sx2[t], p2) - fmaxf(sx1[t], p1); iw = fmaxf(iw, 0.0f);
                float ih = fminf(sy2[t], q2) - fmaxf(sy1[t], q1); ih = fmaxf(ih, 0.0f);
                float inter = iw * ih;
                // iou >= 0.5  <=>  2*inter >= area1 + area2 - inter + eps  (denom > 0)
                ignore = ignore || (inter + inter >= sar[t] + area2c - inter);
                istgt = istgt || (scell[t] == idx);
            }
            float noobj = (!ignore && !istgt) ? -logf(fmaxf(1.0f - conf, 1e-12f)) : 0.0f;
            float aterm = (sx - 0.5f) * (sx - 0.5f) + (sy - 0.5f) * (sy - 0.5f) + wr * wr + hr * hr;
            term = noobj + 0.05f * aterm;              // pre-weighted: 5*0.2=1, 0.1/2=0.05
        }
        red[tid] = term; __syncthreads();
        for (int s = 128; s > 0; s >>= 1) { if (tid < s) red[tid] += red[tid + s]; __syncthreads(); }
        if (tid == 0) ws[blockIdx.x] = red[0];
    } else {
        // ---------------- obj role (one target per block) ----------------
        const int i = blockIdx.x - NCELLBLK;           // target index
        const int b = i / TPER;
        const int t = i - b * TPER;
        if (tid < TPER) {
            const float* p = tgt + (size_t)(b * TPER + tid) * 5;
            float c0 = p[0], c1 = p[1], c2 = p[2], c3 = p[3], c4 = p[4];
            bool valid = (c0 + c1 + c2 + c3 + c4) > 0.0f;
            float gx = c1 * WW, gy = c2 * HH, gw = c3 * WW, gh = c4 * HH;
            int gi = (int)gx; gi = gi < 0 ? 0 : (gi > WW - 1 ? WW - 1 : gi);
            int gj = (int)gy; gj = gj < 0 ? 0 : (gj > HH - 1 ? HH - 1 : gj);
            int bn = 0; float best = -1.0f;
            for (int a = 0; a < 3; ++a) {
                float inter = fminf(gw, aw[a]) * fminf(gh, ah[a]);
                float uni = gw * gh + aw[a] * ah[a] - inter;
                float iou = inter / (uni + 1e-16f);
                if (iou > best) { best = iou; bn = a; }
            }
            scell[tid] = valid ? (bn * HW + gj * WW + gi) : -1;
            int cls = (int)c0; cls = cls < 0 ? 0 : (cls > NC - 1 ? NC - 1 : cls);
            scls[tid] = cls;
        }
        __syncthreads();
        const int cell = scell[t];
        if (tid == 0) ws[NBLK + i] = (cell >= 0) ? 1.0f : 0.0f;   // valid flag
        bool owner = (cell >= 0);
        if (owner) {
            for (int t2 = t + 1; t2 < TPER; ++t2)
                if (scell[t2] == cell) { owner = false; break; }  // later target wins
        }
        if (!owner) {                                  // uniform across block — safe
            if (tid == 0) ws[blockIdx.x] = 0.0f;
            return;
        }
        const int a = cell / HW;
        const int r = cell - a * HW;
        const float* base = in + ((size_t)b * (NA * CH) + a * CH) * HW + r;
        float cterm = 0.0f;
        if (tid < NC) {
            bool pos = false;                          // multi-hot union on collision
            for (int t2 = 0; t2 < TPER; ++t2)
                if (scell[t2] == cell && scls[t2] == tid) { pos = true; break; }
            float p = sigm(base[(size_t)(5 + tid) * HW]);
            cterm = pos ? -logf(fmaxf(p, 1e-12f)) : -logf(fmaxf(1.0f - p, 1e-12f));
        } else if (tid < 85) {
            int k = tid - NC;                          // 0..4 -> x,y,w,h,conf
            float v = base[(size_t)k * HW];
            const float* p = tgt + (size_t)i * 5;
            float term;
            if (k == 0) {
                float gx = p[1] * WW; int gi = (int)gx; gi = gi < 0 ? 0 : (gi > WW - 1 ? WW - 1 : gi);
                float d = sigm(v) - (gx - (float)gi); term = d * d;
            } else if (k == 1) {
                float gy = p[2] * HH; int gj = (int)gy; gj = gj < 0 ? 0 : (gj > HH - 1 ? HH - 1 : gj);
                float d = sigm(v) - (gy - (float)gj); term = d * d;
            } else if (k == 2) {
                float d = v - logf(p[3] * WW / aw[a] + 1e-16f); term = d * d;
            } else if (k == 3) {
                float d = v - logf(p[4] * HH / ah[a] + 1e-16f); term = d * d;
            } else {
                term = -logf(fmaxf(sigm(v), 1e-12f));
            }
            sterm[k] = term;
        }
        red[tid] = cterm; __syncthreads();
        for (int s = 128; s > 0; s >>= 1) { if (tid < s) red[tid] += red[tid + s]; __syncthreads(); }
        if (tid == 0)                                  // pre-weighted contribution
            ws[blockIdx.x] = 0.5f * (sterm[0] + sterm[1] + sterm[2] + sterm[3])
                           + 5.0f * sterm[4] + red[0];
    }
}

// Tiny final reduce: loss = sum(partials) / max(n_valid, 1)
__global__ __launch_bounds__(256) void k_final(const float* __restrict__ ws,
                                               float* __restrict__ out)
{
    const int tid = threadIdx.x;
    float s = 0.0f, nv = 0.0f;
    for (int i = tid; i < NBLK; i += 256) s += ws[i];
    for (int i = tid; i < NTT; i += 256) nv += ws[NBLK + i];
    __shared__ float red[256];
    red[tid] = s; __syncthreads();
    for (int st = 128; st > 0; st >>= 1) { if (tid < st) red[tid] += red[tid + st]; __syncthreads(); }
    float S = red[0]; __syncthreads();
    red[tid] = nv; __syncthreads();
    for (int st = 128; st > 0; st >>= 1) { if (tid < st) red[tid] += red[tid + st]; __syncthreads(); }
    if (tid == 0) out[0] = S / fmaxf(red[0], 1.0f);
}

extern "C" void kernel_launch(void* const* d_in, const int* in_sizes, int n_in,
                              void* d_out, int out_size, void* d_ws, size_t ws_size,
                              hipStream_t stream)
{
    const float* in = (const float*)d_in[0];
    const float* tgt = (const float*)d_in[1];
    float* ws = (float*)d_ws;

    k_main<<<NBLK, 256, 0, stream>>>(in, tgt, ws);
    k_final<<<1, 256, 0, stream>>>(ws, (float*)d_out);
}

// Round 5
// 22.007 us; speedup vs baseline: 4.5272x; 1.4224x over previous
//
#include <hip/hip_runtime.h>
#include <math.h>

// Problem constants (match reference setup_inputs)
#define BS 32
#define NA 3
#define NC 80
#define HH 52
#define WW 52
#define TPER 50                 // targets per batch image
#define NTT (BS * TPER)         // 1600 total targets
#define HW (HH * WW)            // 2704
#define CPB (NA * HW)           // 8112 cells per batch image
#define CH (5 + NC)             // 85 channels per anchor
#define CELLS_PER_BLK 1024      // 256 threads x 4 cells each
#define CBPB 8                  // cell-blocks per batch: 8*1024 >= 8112
#define NCELLBLK (BS * CBPB)    // 256 cells-role blocks
#define NBLK (NCELLBLK + NTT)   // 1856 blocks total (even)

__device__ __forceinline__ float sigm(float v) { return 1.0f / (1.0f + expf(-v)); }

// ws layout: float2 ws[NBLK] = {pre-weighted loss partial, valid-target flag}
// (cells blocks write flag 0; obj block i writes flag = valid(target i))

__global__ __launch_bounds__(256) void k_main(const float* __restrict__ in,
                                              const float* __restrict__ tgt,
                                              float2* __restrict__ ws)
{
    __shared__ float4 sbox[TPER];                 // {x1, x2, y1, y2}
    __shared__ unsigned sbm[CELLS_PER_BLK / 32];  // target-cell bitmap for this block
    __shared__ int scell[TPER], scls[TPER];
    __shared__ float red[256];
    __shared__ float sterm[5];
    const int tid = threadIdx.x;
    const float aw[3] = {1.25f, 2.0f, 4.125f};
    const float ah[3] = {1.625f, 3.75f, 2.875f};

    if (blockIdx.x < NCELLBLK) {
        // ---------------- cells role: noobj BCE + a_loss, 4 cells/thread ----------------
        const int b  = blockIdx.x >> 3;           // / CBPB
        const int yb = blockIdx.x & 7;
        const int lo = yb * CELLS_PER_BLK;
        if (tid < CELLS_PER_BLK / 32) sbm[tid] = 0u;
        int mycell = -1;
        if (tid < TPER) {
            const float* p = tgt + (size_t)(b * TPER + tid) * 5;
            float c0 = p[0], c1 = p[1], c2 = p[2], c3 = p[3], c4 = p[4];
            bool valid = (c0 + c1 + c2 + c3 + c4) > 0.0f;
            float gx = c1 * WW, gy = c2 * HH, gw = c3 * WW, gh = c4 * HH;
            int gi = (int)gx; gi = gi < 0 ? 0 : (gi > WW - 1 ? WW - 1 : gi);
            int gj = (int)gy; gj = gj < 0 ? 0 : (gj > HH - 1 ? HH - 1 : gj);
            int bn = 0; float best = -1.0f;
            for (int a = 0; a < 3; ++a) {
                float inter = fminf(gw, aw[a]) * fminf(gh, ah[a]);
                float uni = gw * gh + aw[a] * ah[a] - inter;
                float iou = inter / (uni + 1e-16f);
                if (iou > best) { best = iou; bn = a; }   // strict >: argmax keeps first
            }
            if (valid) {
                sbox[tid] = make_float4(gx - 0.5f * gw, gx + 0.5f * gw,
                                        gy - 0.5f * gh, gy + 0.5f * gh);
                mycell = bn * HW + gj * WW + gi;
            } else {
                sbox[tid] = make_float4(1e30f, 1e30f, 1e30f, 1e30f);  // inert sentinel
            }
        }
        __syncthreads();
        if (mycell >= lo && mycell < lo + CELLS_PER_BLK)
            atomicOr(&sbm[(mycell - lo) >> 5], 1u << ((mycell - lo) & 31));
        __syncthreads();

        const int idx0 = lo + tid;
        float term = 0.0f;
        float P1[4], P2[4], Q1[4], Q2[4], A2[4], CF[4];
        bool ACT[4];
        #pragma unroll
        for (int k = 0; k < 4; ++k) {
            int idx = idx0 + k * 256;
            ACT[k] = idx < CPB;
            P1[k] = 0.0f; P2[k] = 0.0f; Q1[k] = 0.0f; Q2[k] = 0.0f;
            A2[k] = 1e30f; CF[k] = 0.5f;
            if (ACT[k]) {
                int a = idx / HW;
                int r = idx - a * HW;
                int yy = r / WW;
                int xx = r - yy * WW;
                const float* base = in + ((size_t)b * (NA * CH) + a * CH) * HW + r;
                float xr = base[0], yr = base[HW], wr = base[2 * HW],
                      hr = base[3 * HW], cr = base[4 * HW];
                float sx = sigm(xr), sy = sigm(yr);
                CF[k] = sigm(cr);
                float px = sx + (float)xx, py = sy + (float)yy;
                float pw = expf(wr) * aw[a], ph = expf(hr) * ah[a];
                P1[k] = px - 0.5f * pw; P2[k] = px + 0.5f * pw;
                Q1[k] = py - 0.5f * ph; Q2[k] = py + 0.5f * ph;
                A2[k] = pw * ph + 1e-16f;
                term += 0.05f * ((sx - 0.5f) * (sx - 0.5f) + (sy - 0.5f) * (sy - 0.5f)
                                 + wr * wr + hr * hr);        // 0.1/2 pre-weight
            }
        }
        bool IGN[4] = {false, false, false, false};
        for (int t = 0; t < TPER; ++t) {
            float4 bx = sbox[t];                              // one ds_read_b128 / target
            float ar = (bx.y - bx.x) * (bx.w - bx.z);         // area1 (0 for sentinel)
            #pragma unroll
            for (int k = 0; k < 4; ++k) {
                float iw = fmaxf(fminf(bx.y, P2[k]) - fmaxf(bx.x, P1[k]), 0.0f);
                float ih = fmaxf(fminf(bx.w, Q2[k]) - fmaxf(bx.z, Q1[k]), 0.0f);
                float inter = iw * ih;
                // iou >= 0.5  <=>  3*inter >= area1 + area2 + eps (denominator > 0)
                IGN[k] = IGN[k] || (3.0f * inter >= ar + A2[k]);
            }
        }
        #pragma unroll
        for (int k = 0; k < 4; ++k) {
            int d = idx0 - lo + k * 256;                      // 0..1023
            bool ist = (sbm[d >> 5] >> (d & 31)) & 1u;
            if (ACT[k] && !IGN[k] && !ist)
                term += -logf(fmaxf(1.0f - CF[k], 1e-12f));   // noobj pre-weight 5*0.2=1
        }
        red[tid] = term; __syncthreads();
        for (int s = 128; s > 0; s >>= 1) { if (tid < s) red[tid] += red[tid + s]; __syncthreads(); }
        if (tid == 0) ws[blockIdx.x] = make_float2(red[0], 0.0f);
    } else {
        // ---------------- obj role: one target per block ----------------
        const int i = blockIdx.x - NCELLBLK;
        const int b = i / TPER;
        const int t = i - b * TPER;
        if (tid < TPER) {
            const float* p = tgt + (size_t)(b * TPER + tid) * 5;
            float c0 = p[0], c1 = p[1], c2 = p[2], c3 = p[3], c4 = p[4];
            bool valid = (c0 + c1 + c2 + c3 + c4) > 0.0f;
            float gx = c1 * WW, gy = c2 * HH, gw = c3 * WW, gh = c4 * HH;
            int gi = (int)gx; gi = gi < 0 ? 0 : (gi > WW - 1 ? WW - 1 : gi);
            int gj = (int)gy; gj = gj < 0 ? 0 : (gj > HH - 1 ? HH - 1 : gj);
            int bn = 0; float best = -1.0f;
            for (int a = 0; a < 3; ++a) {
                float inter = fminf(gw, aw[a]) * fminf(gh, ah[a]);
                float uni = gw * gh + aw[a] * ah[a] - inter;
                float iou = inter / (uni + 1e-16f);
                if (iou > best) { best = iou; bn = a; }
            }
            scell[tid] = valid ? (bn * HW + gj * WW + gi) : -1;
            int cls = (int)c0; cls = cls < 0 ? 0 : (cls > NC - 1 ? NC - 1 : cls);
            scls[tid] = cls;
        }
        __syncthreads();
        const int cell = scell[t];                 // broadcast
        const int lane = tid & 63;
        bool m = false;
        if (lane < TPER && cell >= 0) m = (scell[lane] == cell);
        unsigned long long mask = __ballot(m);     // matching valid targets (uniform/wave)
        bool owner = (cell >= 0) && ((mask >> (t + 1)) == 0ULL);  // no later writer
        if (!owner) {                              // uniform across block — safe
            if (tid == 0) ws[blockIdx.x] = make_float2(0.0f, cell >= 0 ? 1.0f : 0.0f);
            return;
        }
        const int a = cell / HW;
        const int r = cell - a * HW;
        const float* base = in + ((size_t)b * (NA * CH) + a * CH) * HW + r;
        float cterm = 0.0f;
        if (tid < NC) {
            bool pos = false;                      // multi-hot union over colliding targets
            unsigned long long mm = mask;
            while (mm) { int t2 = __ffsll(mm) - 1; mm &= mm - 1; pos = pos || (scls[t2] == tid); }
            float p = sigm(base[(size_t)(5 + tid) * HW]);
            cterm = pos ? -logf(fmaxf(p, 1e-12f)) : -logf(fmaxf(1.0f - p, 1e-12f));
        } else if (tid < 85) {
            int k = tid - NC;                      // 0..4 -> x,y,w,h,conf
            float v = base[(size_t)k * HW];
            const float* p = tgt + (size_t)i * 5;
            float term;
            if (k == 0) {
                float gx = p[1] * WW; int gi = (int)gx; gi = gi < 0 ? 0 : (gi > WW - 1 ? WW - 1 : gi);
                float d = sigm(v) - (gx - (float)gi); term = d * d;
            } else if (k == 1) {
                float gy = p[2] * HH; int gj = (int)gy; gj = gj < 0 ? 0 : (gj > HH - 1 ? HH - 1 : gj);
                float d = sigm(v) - (gy - (float)gj); term = d * d;
            } else if (k == 2) {
                float d = v - logf(p[3] * WW / aw[a] + 1e-16f); term = d * d;
            } else if (k == 3) {
                float d = v - logf(p[4] * HH / ah[a] + 1e-16f); term = d * d;
            } else {
                term = -logf(fmaxf(sigm(v), 1e-12f));
            }
            sterm[k] = term;
        }
        red[tid] = cterm; __syncthreads();
        for (int s = 128; s > 0; s >>= 1) { if (tid < s) red[tid] += red[tid + s]; __syncthreads(); }
        if (tid == 0)
            ws[blockIdx.x] = make_float2(0.5f * (sterm[0] + sterm[1] + sterm[2] + sterm[3])
                                         + 5.0f * sterm[4] + red[0], 1.0f);
    }
}

// Final reduce: loss = sum(partials) / max(n_valid, 1). 928 float4 loads.
__global__ __launch_bounds__(256) void k_final(const float2* __restrict__ ws,
                                               float* __restrict__ out)
{
    const int tid = threadIdx.x;
    const float4* w4 = (const float4*)ws;          // NBLK/2 float4
    float s = 0.0f, nv = 0.0f;
    for (int i = tid; i < NBLK / 2; i += 256) {
        float4 v = w4[i];
        s += v.x + v.z;
        nv += v.y + v.w;
    }
    __shared__ float red[256];
    red[tid] = s; __syncthreads();
    for (int st = 128; st > 0; st >>= 1) { if (tid < st) red[tid] += red[tid + st]; __syncthreads(); }
    float S = red[0]; __syncthreads();
    red[tid] = nv; __syncthreads();
    for (int st = 128; st > 0; st >>= 1) { if (tid < st) red[tid] += red[tid + st]; __syncthreads(); }
    if (tid == 0) out[0] = S / fmaxf(red[0], 1.0f);
}

extern "C" void kernel_launch(void* const* d_in, const int* in_sizes, int n_in,
                              void* d_out, int out_size, void* d_ws, size_t ws_size,
                              hipStream_t stream)
{
    const float* in = (const float*)d_in[0];
    const float* tgt = (const float*)d_in[1];
    float2* ws = (float2*)d_ws;

    k_main<<<NBLK, 256, 0, stream>>>(in, tgt, ws);
    k_final<<<1, 256, 0, stream>>>(ws, (float*)d_out);
}